// Round 9
// baseline (405.800 us; speedup 1.0000x reference)
//
#include <hip/hip_runtime.h>
#include <hip/hip_bf16.h>

#define NN   19
#define DIN  100
#define HID  128
#define TT   250
#define BB   64
#define NC   4
#define FEAT 2432          // NN*HID

typedef __attribute__((ext_vector_type(8))) short s8v;
typedef __attribute__((ext_vector_type(4))) float f4v;
typedef _Float16 h8v __attribute__((ext_vector_type(8)));
typedef _Float16 h4v __attribute__((ext_vector_type(4)));

// =============== V2 workspace layout (byte offsets) ===============
// BFI: W_ih MFMA B-frags f16    (19*8*4*4*512 halfs)
// BFH: W_hh MFMA B-frags f16    (same count)
// BIAS: combined b_ih+b_hh f32  (19*512)
// W1T: W1 transposed f32        (2432*128)
// HF : final hidden f32         (64*2432)
// XG : precomputed x-gates f16, slot-grouped fragment layout:
//      f16 element (n,bq,t, wp, lanep, slot, nt) at
//      ((n*4+bq)*250+t)*8192 + (wp*64+lanep)*16 + slot*4 + nt
#define BFI_USH   1245184
#define V2_OFF_BFI  0ull
#define V2_OFF_BFH  2490368ull
#define V2_OFF_BIAS 4980736ull
#define V2_OFF_W1T  5019648ull
#define V2_OFF_HF   6264832ull
#define V2_OFF_XG   6887424ull
#define V2_NEED     318183424ull
#define PACK2_TOTAL (2*BFI_USH + 19*512 + FEAT*HID)

// =============== fallback (round-3) layout, float offsets =========
#define SZ_BF   (NN*8*4*8*512)
#define OFF_W1T_O (SZ_BF/2)
#define SZ_W1T  (FEAT*HID)
#define OFF_HF_O  (OFF_W1T_O + SZ_W1T)
#define PACK_TOTAL_O (SZ_BF + SZ_W1T)

__device__ __forceinline__ unsigned short f2bf(float x) {
    union { float f; unsigned u; } v; v.f = x;
    unsigned r = v.u + 0x7FFF + ((v.u >> 16) & 1);   // RNE
    return (unsigned short)(r >> 16);
}
#define LOG2E 1.4426950408889634f
__device__ __forceinline__ float sigf(float x) {
    return __builtin_amdgcn_rcpf(1.f + __builtin_amdgcn_exp2f(-LOG2E * x));
}
__device__ __forceinline__ float tnhf(float x) {
    return 1.f - 2.f * __builtin_amdgcn_rcpf(__builtin_amdgcn_exp2f(2.f * LOG2E * x) + 1.f);
}

// ======================= V2 kernels ===============================

// Pack W_ih frags, W_hh frags (f16), combined bias, W1T.
// Frag element (n, hb, nt, kt, lane, e) = W[k][g]:
// k = kt*32+(lane>>4)*8+e, g = nt*128+hb*16+(lane&15).
__global__ __launch_bounds__(256) void pack2_kernel(
        const float* __restrict__ W_ih, const float* __restrict__ W_hh,
        const float* __restrict__ b_ih, const float* __restrict__ b_hh,
        const float* __restrict__ W1, char* __restrict__ wsb) {
    int id = blockIdx.x * 256 + threadIdx.x;
    if (id < 2 * BFI_USH) {
        int which = id >= BFI_USH;                 // 0 = W_ih, 1 = W_hh
        int i = which ? id - BFI_USH : id;
        int e    = i & 7;
        int lane = (i >> 3) & 63;
        int kt   = (i >> 9) & 3;
        int nt   = (i >> 11) & 3;
        int hb   = (i >> 13) & 7;
        int n    = i >> 16;
        int k = kt * 32 + (lane >> 4) * 8 + e;
        int g = nt * 128 + hb * 16 + (lane & 15);
        float v;
        if (which) v = W_hh[((size_t)n * 512 + g) * HID + k];
        else       v = (k < DIN) ? W_ih[((size_t)n * 512 + g) * DIN + k] : 0.f;
        reinterpret_cast<_Float16*>(wsb)[id] = (_Float16)v;
        return;
    }
    int id2 = id - 2 * BFI_USH;
    if (id2 < NN * 512) {
        reinterpret_cast<float*>(wsb + V2_OFF_BIAS)[id2] = b_ih[id2] + b_hh[id2];
        return;
    }
    int id3 = id2 - NN * 512;
    if (id3 < FEAT * HID) {
        int j = id3 & 127, k = id3 >> 7;
        reinterpret_cast<float*>(wsb + V2_OFF_W1T)[id3] = W1[(size_t)j * FEAT + k];
    }
}

// xg GEMM: grid = (n, bq, tchunk of 25). 512 thr = 8 waves. f16 path.
// Stores C-fragments SLOT-GROUPED: s0[nt]=acc[nt][0], s0[4+nt]=acc[nt][1],
// s1[nt]=acc[nt][2], s1[4+nt]=acc[nt][3], so a consumer thread can fetch
// (slot r, slot r+1) x 4 gates as one contiguous 16B load.
__global__ __launch_bounds__(512, 2) void xg_kernel(
        const float* __restrict__ inp, const char* __restrict__ wsb,
        _Float16* __restrict__ xg) {
    __shared__ alignas(16) _Float16 xa[2][16 * 128];

    const int tid  = threadIdx.x;
    const int lane = tid & 63;
    const int w    = tid >> 6;
    const int l15  = lane & 15;
    const int g4   = lane >> 4;
    const int blk  = blockIdx.x;
    const int tc   = blk % 10;
    const int bq   = (blk / 10) & 3;
    const int n    = blk / 40;
    const int t0   = tc * 25;
    const int j    = w * 16 + l15;

    h8v bf[4][4];
    {
        const _Float16* wp = reinterpret_cast<const _Float16*>(wsb)
                             + ((size_t)(n * 8 + w) * 16) * 512 + lane * 8;
        #pragma unroll
        for (int nt = 0; nt < 4; ++nt)
            #pragma unroll
            for (int kt = 0; kt < 4; ++kt)
                bf[nt][kt] = *reinterpret_cast<const h8v*>(wp + (nt * 4 + kt) * 512);
    }
    float bs[4];
    #pragma unroll
    for (int nt = 0; nt < 4; ++nt)
        bs[nt] = reinterpret_cast<const float*>(wsb + V2_OFF_BIAS)[n * 512 + nt * 128 + j];

    for (int i = tid; i < 2 * 16 * 128; i += 512) (&xa[0][0])[i] = (_Float16)0.f;

    const bool st = tid < 400;
    const int row = st ? tid / 25 : 0;
    const int c4  = st ? tid - row * 25 : 0;
    const float* xb = inp + ((size_t)(bq * 16 + row) * NN + n) * (TT * DIN)
                      + (size_t)t0 * DIN + c4 * 4;
    const int wofs = row * 256 + ((c4 * 8) ^ ((row & 7) << 4));
    const int arow = l15 * 256;
    const int aswz = (l15 & 7) << 4;

    __syncthreads();
    if (st) {
        float4 v = *reinterpret_cast<const float4*>(xb);
        h4v pk = {(_Float16)v.x, (_Float16)v.y, (_Float16)v.z, (_Float16)v.w};
        *reinterpret_cast<h4v*>(reinterpret_cast<char*>(xa[0]) + wofs) = pk;
    }
    __syncthreads();

    _Float16* xout = xg + ((size_t)((n * 4 + bq) * 250 + t0)) * 8192
                     + (w * 64 + lane) * 16;

    for (int t = 0; t < 25; ++t) {
        char* rc = reinterpret_cast<char*>(xa[t & 1]);
        char* wc = reinterpret_cast<char*>(xa[(t + 1) & 1]);

        float4 nxt = make_float4(0.f, 0.f, 0.f, 0.f);
        if (t < 24 && st)
            nxt = *reinterpret_cast<const float4*>(xb + (t + 1) * DIN);

        f4v acc[4];
        #pragma unroll
        for (int nt = 0; nt < 4; ++nt)
            acc[nt] = (f4v){bs[nt], bs[nt], bs[nt], bs[nt]};
        #pragma unroll
        for (int kt = 0; kt < 4; ++kt) {
            h8v a = *reinterpret_cast<const h8v*>(
                        rc + arow + ((kt * 64 + g4 * 16) ^ aswz));
            #pragma unroll
            for (int nt = 0; nt < 4; ++nt)
                acc[nt] = __builtin_amdgcn_mfma_f32_16x16x32_f16(
                              a, bf[nt][kt], acc[nt], 0, 0, 0);
        }

        // slot-grouped store for the consumer
        h8v s0, s1;
        #pragma unroll
        for (int nt = 0; nt < 4; ++nt) {
            s0[nt]     = (_Float16)acc[nt][0];
            s0[4 + nt] = (_Float16)acc[nt][1];
            s1[nt]     = (_Float16)acc[nt][2];
            s1[4 + nt] = (_Float16)acc[nt][3];
        }
        *reinterpret_cast<h8v*>(xout + (size_t)t * 8192)     = s0;
        *reinterpret_cast<h8v*>(xout + (size_t)t * 8192 + 8) = s1;

        if (t < 24 && st) {
            h4v pk = {(_Float16)nxt.x, (_Float16)nxt.y, (_Float16)nxt.z, (_Float16)nxt.w};
            *reinterpret_cast<h4v*>(wc + wofs) = pk;
        }
        __syncthreads();
    }
}

// Recurrence v6: grid 152 = (n, batch-octet). 512 thr = 8 waves =
// TWO GANGS split by hidden-half (gang ha owns j in [ha*64, ha*64+64)).
// Per SIMD: 2 independent wave streams, 2x16 = 32 MFMA/step (same pipe
// floor as r7's 1-wave config, but stalls now hidden by the second wave).
// A-tile: r7's permuted zero-padded map — tile row g4*4+q (q=0,1) holds
// real row R=(g4&1)*4+(g4>>1)*2+q; tile rows with q>=2 stay zero.
// Each thread: ONE hidden j, rows R(g4,0/1) -> 2 gate-sets, one 16B xg load.
__global__ __launch_bounds__(512, 2) void lstm6_kernel(
        const char* __restrict__ wsb, const _Float16* __restrict__ xg,
        float* __restrict__ hf) {
    __shared__ alignas(16) _Float16 xh[2][16 * 128];

    const int tid  = threadIdx.x;
    const int lane = tid & 63;
    const int w8   = tid >> 6;          // 0..7
    const int ha   = w8 >> 2;           // hidden half (gang)
    const int wv   = w8 & 3;            // wave within gang
    const int l15  = lane & 15;
    const int g4   = lane >> 4;
    const int n    = blockIdx.x >> 3;
    const int oct  = blockIdx.x & 7;
    const int bq   = oct >> 1;
    const int hi   = oct & 1;
    const int hb   = ha * 4 + wv;       // hidden block 0..7
    const int j    = hb * 16 + l15;     // this thread's hidden index

    // W_hh frags for this wave's j-block: 16 h8v = 64 VGPR
    h8v bf[4][4];
    {
        const _Float16* wp = reinterpret_cast<const _Float16*>(wsb + V2_OFF_BFH)
                             + (size_t)lane * 8;
        #pragma unroll
        for (int nt = 0; nt < 4; ++nt)
            #pragma unroll
            for (int kt = 0; kt < 4; ++kt)
                bf[nt][kt] = *reinterpret_cast<const h8v*>(
                    wp + ((size_t)((n * 8 + hb) * 16 + nt * 4 + kt)) * 512);
    }

    float c2[2] = {0.f, 0.f};
    float h2[2] = {0.f, 0.f};

    for (int i = tid; i < 2 * 16 * 128; i += 512) (&xh[0][0])[i] = (_Float16)0.f;

    // xg source: producer tile row tr_p = hi*8 + R(g4,q) -> lanep/slot:
    // lanep = l15 + 16*(hi*2+(g4&1)), slots (g4>>1)*2 + q  (contiguous pair)
    const _Float16* xp = xg + ((size_t)((n * 4 + bq) * 250)) * 8192
        + (size_t)(hb * 64 + l15 + 16 * (hi * 2 + (g4 & 1))) * 16
        + (g4 >> 1) * 8;

    const int arow = l15 * 256;
    const int aswz = (l15 & 7) << 4;
    // h-writes: tile rows g4*4+q, col j
    const int wr0 = (g4 * 4) * 256 + ((2 * j) ^ (((g4 * 4) & 7) << 4));
    const int wr1 = (g4 * 4 + 1) * 256 + ((2 * j) ^ (((g4 * 4 + 1) & 7) << 4));

    // 2-deep prefetch rotation
    h8v p  = *reinterpret_cast<const h8v*>(xp);
    h8v qn = *reinterpret_cast<const h8v*>(xp + 8192);
    __syncthreads();

    for (int t = 0; t < TT; ++t) {
        char* rc = reinterpret_cast<char*>(xh[t & 1]);
        char* wc = reinterpret_cast<char*>(xh[(t + 1) & 1]);

        int tn = t + 2 < TT ? t + 2 : TT - 1;      // uniform clamp
        h8v rn = *reinterpret_cast<const h8v*>(xp + (size_t)tn * 8192);

        // acc init: slot0 = xg(q=0), slot1 = xg(q=1); slots 2,3 don't-care
        f4v acc[4];
        #pragma unroll
        for (int nt = 0; nt < 4; ++nt)
            acc[nt] = (f4v){(float)p[nt], (float)p[4 + nt], 0.f, 0.f};

        #pragma unroll
        for (int kt = 0; kt < 4; ++kt) {
            h8v a = *reinterpret_cast<const h8v*>(
                        rc + arow + ((kt * 64 + g4 * 16) ^ aswz));
            #pragma unroll
            for (int nt = 0; nt < 4; ++nt)
                acc[nt] = __builtin_amdgcn_mfma_f32_16x16x32_f16(
                              a, bf[nt][kt], acc[nt], 0, 0, 0);
        }

        // phase 3: static slots 0,1 — 2 gate-sets per thread
        #pragma unroll
        for (int q = 0; q < 2; ++q) {
            float ii = sigf(acc[0][q]);
            float ff = sigf(acc[1][q]);
            float gg = tnhf(acc[2][q]);
            float oo = sigf(acc[3][q]);
            float cn = ff * c2[q] + ii * gg;
            c2[q] = cn;
            float hn = oo * tnhf(cn);
            h2[q] = hn;
            *reinterpret_cast<_Float16*>(wc + (q ? wr1 : wr0)) = (_Float16)hn;
        }
        p = qn; qn = rn;
        __syncthreads();
    }

    #pragma unroll
    for (int q = 0; q < 2; ++q) {
        int b = bq * 16 + hi * 8 + (g4 & 1) * 4 + (g4 >> 1) * 2 + q;
        hf[((size_t)b * NN + n) * HID + j] = h2[q];
    }
}

// Head: 64 blocks (one per batch row), 256 thr, split-K over 2 halves.
__global__ __launch_bounds__(256) void head2_kernel(
        const float* __restrict__ hf, const float* __restrict__ w1t,
        const float* __restrict__ b1, const float* __restrict__ W2,
        const float* __restrict__ b2, float* __restrict__ out) {
    __shared__ float comb[FEAT];
    __shared__ float par[2][HID];
    __shared__ float hid[HID];
    const int b = blockIdx.x;
    const int u  = threadIdx.x & 127;
    const int kk = threadIdx.x >> 7;
    const float* hfp = hf + (size_t)b * FEAT;
    for (int i = threadIdx.x; i < FEAT; i += 256) comb[i] = hfp[i];
    __syncthreads();

    const int k0 = kk * (FEAT / 2);
    float acc = 0.f;
    #pragma unroll 8
    for (int k = 0; k < FEAT / 2; ++k)
        acc = fmaf(comb[k0 + k], w1t[(size_t)(k0 + k) * HID + u], acc);
    par[kk][u] = acc;
    __syncthreads();
    if (kk == 0) hid[u] = fmaxf(par[0][u] + par[1][u] + b1[u], 0.f);
    __syncthreads();

    if (threadIdx.x < NC) {
        int cls = threadIdx.x;
        float a = b2[cls];
        #pragma unroll 4
        for (int k = 0; k < HID; ++k)
            a = fmaf(hid[k], W2[cls * HID + k], a);
        out[b * NC + cls] = a;
    }
}

// ======================= fallback (round-3) =======================
__global__ __launch_bounds__(256) void packfb_kernel(
        const float* __restrict__ W_ih, const float* __restrict__ W_hh,
        const float* __restrict__ W1,
        unsigned short* __restrict__ bfw, float* __restrict__ w1t) {
    int id = blockIdx.x * 256 + threadIdx.x;
    if (id < SZ_BF) {
        int e    = id & 7;
        int lane = (id >> 3) & 63;
        int kt   = (id >> 9) & 7;
        int nt   = (id >> 12) & 3;
        int hb   = (id >> 14) & 7;
        int n    = id >> 17;
        int k = kt * 32 + (lane >> 4) * 8 + e;
        int g = nt * 128 + hb * 16 + (lane & 15);
        float v = 0.f;
        if (k < DIN)       v = W_ih[((size_t)n * 512 + g) * DIN + k];
        else if (k < 228)  v = W_hh[((size_t)n * 512 + g) * HID + (k - DIN)];
        bfw[id] = f2bf(v);
        return;
    }
    int id3 = id - SZ_BF;
    if (id3 < SZ_W1T) {
        int j = id3 & 127, k = id3 >> 7;
        w1t[id3] = W1[(size_t)j * FEAT + k];
    }
}

__global__ __launch_bounds__(512, 2) void lstmfb_kernel(
        const float* __restrict__ inp,
        const float* __restrict__ b_ih, const float* __restrict__ b_hh,
        const unsigned short* __restrict__ bfw, float* __restrict__ hf) {
    __shared__ alignas(16) unsigned short xh[2][16 * 256];
    const int tid  = threadIdx.x;
    const int lane = tid & 63;
    const int w    = tid >> 6;
    const int l15  = lane & 15;
    const int g4   = lane >> 4;
    const int n    = blockIdx.x >> 2;
    const int bq   = blockIdx.x & 3;
    const int j    = w * 16 + l15;

    s8v bf[4][8];
    const unsigned short* wp = bfw + ((size_t)(n * 8 + w) * 32) * 512 + lane * 8;
    #pragma unroll
    for (int nt = 0; nt < 4; ++nt)
        #pragma unroll
        for (int kt = 0; kt < 8; ++kt)
            bf[nt][kt] = *reinterpret_cast<const s8v*>(wp + (nt * 8 + kt) * 512);

    float bs[4];
    #pragma unroll
    for (int nt = 0; nt < 4; ++nt)
        bs[nt] = b_ih[n * 512 + nt * 128 + j] + b_hh[n * 512 + nt * 128 + j];

    float c[4] = {0.f, 0.f, 0.f, 0.f};
    float h[4] = {0.f, 0.f, 0.f, 0.f};
    for (int i = tid; i < 2 * 16 * 256; i += 512) (&xh[0][0])[i] = 0;

    const bool st = tid < 400;
    const int row = st ? tid / 25 : 0;
    const int c4  = st ? tid - row * 25 : 0;
    const float* xb = inp + ((size_t)(bq * 16 + row) * NN + n) * (TT * DIN) + c4 * 4;
    const int wofs = row * 512 + ((c4 * 8) ^ ((row & 7) << 4));
    const int arow = l15 * 512;
    const int aswz = (l15 & 7) << 4;

    __syncthreads();
    if (st) {
        float4 v = *reinterpret_cast<const float4*>(xb);
        unsigned lo = f2bf(v.x) | ((unsigned)f2bf(v.y) << 16);
        unsigned hi = f2bf(v.z) | ((unsigned)f2bf(v.w) << 16);
        *reinterpret_cast<uint2*>(reinterpret_cast<char*>(xh[0]) + wofs) =
            make_uint2(lo, hi);
    }
    __syncthreads();

    for (int t = 0; t < TT; ++t) {
        char* rc = reinterpret_cast<char*>(xh[t & 1]);
        char* wc = reinterpret_cast<char*>(xh[(t + 1) & 1]);
        float4 nxt = make_float4(0.f, 0.f, 0.f, 0.f);
        if (t < TT - 1 && st)
            nxt = *reinterpret_cast<const float4*>(xb + (t + 1) * DIN);

        f4v acc[4];
        #pragma unroll
        for (int nt = 0; nt < 4; ++nt)
            acc[nt] = (f4v){bs[nt], bs[nt], bs[nt], bs[nt]};
        #pragma unroll
        for (int kt = 0; kt < 8; ++kt) {
            s8v a = *reinterpret_cast<const s8v*>(rc + arow + ((kt * 64 + g4 * 16) ^ aswz));
            #pragma unroll
            for (int nt = 0; nt < 4; ++nt)
                acc[nt] = __builtin_amdgcn_mfma_f32_16x16x32_bf16(a, bf[nt][kt], acc[nt], 0, 0, 0);
        }
        #pragma unroll
        for (int r = 0; r < 4; ++r) {
            float ii = sigf(acc[0][r]);
            float ff = sigf(acc[1][r]);
            float gg = tnhf(acc[2][r]);
            float oo = sigf(acc[3][r]);
            float cn = ff * c[r] + ii * gg;
            c[r] = cn;
            float hn = oo * tnhf(cn);
            h[r] = hn;
            int rr = g4 * 4 + r;
            *reinterpret_cast<unsigned short*>(
                wc + rr * 512 + (((DIN + j) * 2) ^ ((rr & 7) << 4))) = f2bf(hn);
        }
        if (t < TT - 1 && st) {
            unsigned lo = f2bf(nxt.x) | ((unsigned)f2bf(nxt.y) << 16);
            unsigned hi = f2bf(nxt.z) | ((unsigned)f2bf(nxt.w) << 16);
            *reinterpret_cast<uint2*>(wc + wofs) = make_uint2(lo, hi);
        }
        __syncthreads();
    }
    #pragma unroll
    for (int r = 0; r < 4; ++r) {
        int b = bq * 16 + g4 * 4 + r;
        hf[((size_t)b * NN + n) * HID + j] = h[r];
    }
}

// ============================ launch ==============================
extern "C" void kernel_launch(void* const* d_in, const int* in_sizes, int n_in,
                              void* d_out, int out_size, void* d_ws, size_t ws_size,
                              hipStream_t stream) {
    const float* inp  = (const float*)d_in[0];
    const float* W_ih = (const float*)d_in[2];
    const float* W_hh = (const float*)d_in[3];
    const float* b_ih = (const float*)d_in[4];
    const float* b_hh = (const float*)d_in[5];
    const float* W1   = (const float*)d_in[6];
    const float* b1   = (const float*)d_in[7];
    const float* W2   = (const float*)d_in[8];
    const float* b2   = (const float*)d_in[9];
    float* out = (float*)d_out;

    if (ws_size >= V2_NEED) {
        char* wsb = (char*)d_ws;
        _Float16* xg = (_Float16*)(wsb + V2_OFF_XG);
        float* hf    = (float*)(wsb + V2_OFF_HF);
        float* w1t   = (float*)(wsb + V2_OFF_W1T);
        pack2_kernel<<<(PACK2_TOTAL + 255) / 256, 256, 0, stream>>>(
            W_ih, W_hh, b_ih, b_hh, W1, wsb);
        xg_kernel<<<NN * 4 * 10, 512, 0, stream>>>(inp, wsb, xg);
        lstm6_kernel<<<NN * 8, 512, 0, stream>>>(wsb, xg, hf);
        head2_kernel<<<BB, 256, 0, stream>>>(hf, w1t, b1, W2, b2, out);
    } else {
        float* ws = (float*)d_ws;
        unsigned short* bfw = (unsigned short*)d_ws;
        packfb_kernel<<<(PACK_TOTAL_O + 255) / 256, 256, 0, stream>>>(
            W_ih, W_hh, W1, bfw, ws + OFF_W1T_O);
        lstmfb_kernel<<<NN * 4, 512, 0, stream>>>(inp, b_ih, b_hh, bfw, ws + OFF_HF_O);
        head2_kernel<<<BB, 256, 0, stream>>>(ws + OFF_HF_O, ws + OFF_W1T_O,
                                             b1, W2, b2, out);
    }
}

// Round 10
// 375.321 us; speedup vs baseline: 1.0812x; 1.0812x over previous
//
#include <hip/hip_runtime.h>
#include <hip/hip_bf16.h>

#define NN   19
#define DIN  100
#define HID  128
#define TT   250
#define BB   64
#define NC   4
#define FEAT 2432          // NN*HID

typedef __attribute__((ext_vector_type(8))) short s8v;
typedef __attribute__((ext_vector_type(4))) float f4v;
typedef _Float16 h8v __attribute__((ext_vector_type(8)));
typedef _Float16 h4v __attribute__((ext_vector_type(4)));

// =============== V2 workspace layout (byte offsets) ===============
#define BFI_USH   1245184
#define V2_OFF_BFI  0ull
#define V2_OFF_BFH  2490368ull
#define V2_OFF_BIAS 4980736ull
#define V2_OFF_W1T  5019648ull
#define V2_OFF_HF   6264832ull
#define V2_OFF_XG   6887424ull
#define V2_NEED     318183424ull
#define PACK2_TOTAL (2*BFI_USH + 19*512 + FEAT*HID)

// =============== fallback (round-3) layout, float offsets =========
#define SZ_BF   (NN*8*4*8*512)
#define OFF_W1T_O (SZ_BF/2)
#define SZ_W1T  (FEAT*HID)
#define OFF_HF_O  (OFF_W1T_O + SZ_W1T)
#define PACK_TOTAL_O (SZ_BF + SZ_W1T)

__device__ __forceinline__ unsigned short f2bf(float x) {
    union { float f; unsigned u; } v; v.f = x;
    unsigned r = v.u + 0x7FFF + ((v.u >> 16) & 1);   // RNE
    return (unsigned short)(r >> 16);
}
#define LOG2E 1.4426950408889634f
__device__ __forceinline__ float sigf(float x) {
    return __builtin_amdgcn_rcpf(1.f + __builtin_amdgcn_exp2f(-LOG2E * x));
}
__device__ __forceinline__ float tnhf(float x) {
    return 1.f - 2.f * __builtin_amdgcn_rcpf(__builtin_amdgcn_exp2f(2.f * LOG2E * x) + 1.f);
}

// lgkm-only barrier: LDS writes drained; global (vmcnt) loads/stores stay
// in flight across the barrier (avoids __syncthreads' vmcnt(0) drain).
__device__ __forceinline__ void lgkm_barrier() {
    asm volatile("s_waitcnt lgkmcnt(0)" ::: "memory");
    __builtin_amdgcn_s_barrier();
    asm volatile("" ::: "memory");
}

// ======================= V2 kernels ===============================

// Pack W_ih frags, W_hh frags (f16), combined bias, W1T.
// Frag element (n, hb, nt, kt, lane, e) = W[k][g]:
// k = kt*32+(lane>>4)*8+e, g = nt*128+hb*16+(lane&15).
__global__ __launch_bounds__(256) void pack2_kernel(
        const float* __restrict__ W_ih, const float* __restrict__ W_hh,
        const float* __restrict__ b_ih, const float* __restrict__ b_hh,
        const float* __restrict__ W1, char* __restrict__ wsb) {
    int id = blockIdx.x * 256 + threadIdx.x;
    if (id < 2 * BFI_USH) {
        int which = id >= BFI_USH;                 // 0 = W_ih, 1 = W_hh
        int i = which ? id - BFI_USH : id;
        int e    = i & 7;
        int lane = (i >> 3) & 63;
        int kt   = (i >> 9) & 3;
        int nt   = (i >> 11) & 3;
        int hb   = (i >> 13) & 7;
        int n    = i >> 16;
        int k = kt * 32 + (lane >> 4) * 8 + e;
        int g = nt * 128 + hb * 16 + (lane & 15);
        float v;
        if (which) v = W_hh[((size_t)n * 512 + g) * HID + k];
        else       v = (k < DIN) ? W_ih[((size_t)n * 512 + g) * DIN + k] : 0.f;
        reinterpret_cast<_Float16*>(wsb)[id] = (_Float16)v;
        return;
    }
    int id2 = id - 2 * BFI_USH;
    if (id2 < NN * 512) {
        reinterpret_cast<float*>(wsb + V2_OFF_BIAS)[id2] = b_ih[id2] + b_hh[id2];
        return;
    }
    int id3 = id2 - NN * 512;
    if (id3 < FEAT * HID) {
        int j = id3 & 127, k = id3 >> 7;
        reinterpret_cast<float*>(wsb + V2_OFF_W1T)[id3] = W1[(size_t)j * FEAT + k];
    }
}

// xg GEMM: grid = (n, bq, tchunk of 25). 512 thr = 8 waves. f16 path.
// Stores C-fragments SLOT-GROUPED: s0[nt]=acc[nt][0], s0[4+nt]=acc[nt][1],
// s1[nt]=acc[nt][2], s1[4+nt]=acc[nt][3].
__global__ __launch_bounds__(512, 2) void xg_kernel(
        const float* __restrict__ inp, const char* __restrict__ wsb,
        _Float16* __restrict__ xg) {
    __shared__ alignas(16) _Float16 xa[2][16 * 128];

    const int tid  = threadIdx.x;
    const int lane = tid & 63;
    const int w    = tid >> 6;
    const int l15  = lane & 15;
    const int g4   = lane >> 4;
    const int blk  = blockIdx.x;
    const int tc   = blk % 10;
    const int bq   = (blk / 10) & 3;
    const int n    = blk / 40;
    const int t0   = tc * 25;
    const int j    = w * 16 + l15;

    h8v bf[4][4];
    {
        const _Float16* wp = reinterpret_cast<const _Float16*>(wsb)
                             + ((size_t)(n * 8 + w) * 16) * 512 + lane * 8;
        #pragma unroll
        for (int nt = 0; nt < 4; ++nt)
            #pragma unroll
            for (int kt = 0; kt < 4; ++kt)
                bf[nt][kt] = *reinterpret_cast<const h8v*>(wp + (nt * 4 + kt) * 512);
    }
    float bs[4];
    #pragma unroll
    for (int nt = 0; nt < 4; ++nt)
        bs[nt] = reinterpret_cast<const float*>(wsb + V2_OFF_BIAS)[n * 512 + nt * 128 + j];

    for (int i = tid; i < 2 * 16 * 128; i += 512) (&xa[0][0])[i] = (_Float16)0.f;

    const bool st = tid < 400;
    const int row = st ? tid / 25 : 0;
    const int c4  = st ? tid - row * 25 : 0;
    const float* xb = inp + ((size_t)(bq * 16 + row) * NN + n) * (TT * DIN)
                      + (size_t)t0 * DIN + c4 * 4;
    const int wofs = row * 256 + ((c4 * 8) ^ ((row & 7) << 4));
    const int arow = l15 * 256;
    const int aswz = (l15 & 7) << 4;

    __syncthreads();
    if (st) {
        float4 v = *reinterpret_cast<const float4*>(xb);
        h4v pk = {(_Float16)v.x, (_Float16)v.y, (_Float16)v.z, (_Float16)v.w};
        *reinterpret_cast<h4v*>(reinterpret_cast<char*>(xa[0]) + wofs) = pk;
    }
    __syncthreads();

    _Float16* xout = xg + ((size_t)((n * 4 + bq) * 250 + t0)) * 8192
                     + (w * 64 + lane) * 16;

    for (int t = 0; t < 25; ++t) {
        char* rc = reinterpret_cast<char*>(xa[t & 1]);
        char* wc = reinterpret_cast<char*>(xa[(t + 1) & 1]);

        float4 nxt = make_float4(0.f, 0.f, 0.f, 0.f);
        if (t < 24 && st)
            nxt = *reinterpret_cast<const float4*>(xb + (t + 1) * DIN);

        f4v acc[4];
        #pragma unroll
        for (int nt = 0; nt < 4; ++nt)
            acc[nt] = (f4v){bs[nt], bs[nt], bs[nt], bs[nt]};
        #pragma unroll
        for (int kt = 0; kt < 4; ++kt) {
            h8v a = *reinterpret_cast<const h8v*>(
                        rc + arow + ((kt * 64 + g4 * 16) ^ aswz));
            #pragma unroll
            for (int nt = 0; nt < 4; ++nt)
                acc[nt] = __builtin_amdgcn_mfma_f32_16x16x32_f16(
                              a, bf[nt][kt], acc[nt], 0, 0, 0);
        }

        h8v s0, s1;
        #pragma unroll
        for (int nt = 0; nt < 4; ++nt) {
            s0[nt]     = (_Float16)acc[nt][0];
            s0[4 + nt] = (_Float16)acc[nt][1];
            s1[nt]     = (_Float16)acc[nt][2];
            s1[4 + nt] = (_Float16)acc[nt][3];
        }
        *reinterpret_cast<h8v*>(xout + (size_t)t * 8192)     = s0;
        *reinterpret_cast<h8v*>(xout + (size_t)t * 8192 + 8) = s1;

        if (t < 24 && st) {
            h4v pk = {(_Float16)nxt.x, (_Float16)nxt.y, (_Float16)nxt.z, (_Float16)nxt.w};
            *reinterpret_cast<h4v*>(wc + wofs) = pk;
        }
        lgkm_barrier();   // global stores stay in flight
    }
}

// Recurrence v7: structure of lstm6 (152 WGs, 8 waves = 2 hidden-half gangs,
// 16 MFMA/wave/step), with:
//  - nt-major MFMA + per-gate early nonlinearity (trans hides under MFMA)
//  - lgkm-only barrier (xg prefetch loads never drained at the barrier)
//  - LDS swizzle f3(row) = ((row&1)<<4)|(((row>>2)&3)<<5): h-writes 2-way
//  - acc-init before prefetch issue; t-loop unrolled 2x
// Tile map (unchanged from lstm6): tile row g4*4+q holds real row
// R = (g4&1)*4+(g4>>1)*2+q of the octet; rows with slot>=2 stay zero.
__global__ __launch_bounds__(512, 2) void lstm7_kernel(
        const char* __restrict__ wsb, const _Float16* __restrict__ xg,
        float* __restrict__ hf) {
    __shared__ alignas(16) _Float16 xh[2][16 * 128];

    const int tid  = threadIdx.x;
    const int lane = tid & 63;
    const int w8   = tid >> 6;          // 0..7
    const int l15  = lane & 15;
    const int g4   = lane >> 4;
    const int n    = blockIdx.x >> 3;
    const int oct  = blockIdx.x & 7;
    const int bq   = oct >> 1;
    const int hi   = oct & 1;
    const int hb   = w8;                // hidden block 0..7 (wave owns 16 j)
    const int j    = hb * 16 + l15;

    // W_hh frags for this wave's j-block: 16 h8v = 64 regs
    h8v bf[4][4];
    {
        const _Float16* wp = reinterpret_cast<const _Float16*>(wsb + V2_OFF_BFH)
                             + (size_t)lane * 8;
        #pragma unroll
        for (int nt = 0; nt < 4; ++nt)
            #pragma unroll
            for (int kt = 0; kt < 4; ++kt)
                bf[nt][kt] = *reinterpret_cast<const h8v*>(
                    wp + ((size_t)((n * 8 + hb) * 16 + nt * 4 + kt)) * 512);
    }

    float c2[2] = {0.f, 0.f};
    float h2[2] = {0.f, 0.f};

    for (int i = tid; i < 2 * 16 * 128; i += 512) (&xh[0][0])[i] = (_Float16)0.f;

    // xg source (unchanged mapping)
    const _Float16* xp = xg + ((size_t)((n * 4 + bq) * 250)) * 8192
        + (size_t)(hb * 64 + l15 + 16 * (hi * 2 + (g4 & 1))) * 16
        + (g4 >> 1) * 8;

    // LDS swizzle f3
    const int arow = l15 * 256;
    const int aswz = ((l15 & 1) << 4) | (((l15 >> 2) & 3) << 5);
    // h-writes: tile rows T0=g4*4 (f3=g4<<5), T1=g4*4+1 (f3=16|(g4<<5))
    const int wr0 = (g4 * 4) * 256 + ((2 * j) ^ (g4 << 5));
    const int wr1 = (g4 * 4 + 1) * 256 + ((2 * j) ^ 16 ^ (g4 << 5));

    // 2-deep prefetch rotation
    h8v p  = *reinterpret_cast<const h8v*>(xp);
    h8v qn = *reinterpret_cast<const h8v*>(xp + 8192);
    lgkm_barrier();

    #pragma unroll 2
    for (int t = 0; t < TT; ++t) {
        char* rc = reinterpret_cast<char*>(xh[t & 1]);
        char* wc = reinterpret_cast<char*>(xh[(t + 1) & 1]);

        // acc init from p (xg loaded 2 steps ago)
        f4v acc[4];
        #pragma unroll
        for (int nt = 0; nt < 4; ++nt)
            acc[nt] = (f4v){(float)p[nt], (float)p[4 + nt], 0.f, 0.f};

        // issue prefetch for t+2 (left in flight across the barrier)
        int tn = t + 2 < TT ? t + 2 : TT - 1;
        h8v rn = *reinterpret_cast<const h8v*>(xp + (size_t)tn * 8192);

        // A-fragments (all 4 up front)
        h8v a0 = *reinterpret_cast<const h8v*>(rc + arow + ((0 * 64 + g4 * 16) ^ aswz));
        h8v a1 = *reinterpret_cast<const h8v*>(rc + arow + ((1 * 64 + g4 * 16) ^ aswz));
        h8v a2 = *reinterpret_cast<const h8v*>(rc + arow + ((2 * 64 + g4 * 16) ^ aswz));
        h8v a3 = *reinterpret_cast<const h8v*>(rc + arow + ((3 * 64 + g4 * 16) ^ aswz));

        // nt-major MFMA; nonlinearity issued as soon as each gate is ready
        acc[0] = __builtin_amdgcn_mfma_f32_16x16x32_f16(a0, bf[0][0], acc[0], 0, 0, 0);
        acc[0] = __builtin_amdgcn_mfma_f32_16x16x32_f16(a1, bf[0][1], acc[0], 0, 0, 0);
        acc[0] = __builtin_amdgcn_mfma_f32_16x16x32_f16(a2, bf[0][2], acc[0], 0, 0, 0);
        acc[0] = __builtin_amdgcn_mfma_f32_16x16x32_f16(a3, bf[0][3], acc[0], 0, 0, 0);
        float ii0 = sigf(acc[0][0]);
        float ii1 = sigf(acc[0][1]);

        acc[1] = __builtin_amdgcn_mfma_f32_16x16x32_f16(a0, bf[1][0], acc[1], 0, 0, 0);
        acc[1] = __builtin_amdgcn_mfma_f32_16x16x32_f16(a1, bf[1][1], acc[1], 0, 0, 0);
        acc[1] = __builtin_amdgcn_mfma_f32_16x16x32_f16(a2, bf[1][2], acc[1], 0, 0, 0);
        acc[1] = __builtin_amdgcn_mfma_f32_16x16x32_f16(a3, bf[1][3], acc[1], 0, 0, 0);
        float ff0 = sigf(acc[1][0]);
        float ff1 = sigf(acc[1][1]);

        acc[2] = __builtin_amdgcn_mfma_f32_16x16x32_f16(a0, bf[2][0], acc[2], 0, 0, 0);
        acc[2] = __builtin_amdgcn_mfma_f32_16x16x32_f16(a1, bf[2][1], acc[2], 0, 0, 0);
        acc[2] = __builtin_amdgcn_mfma_f32_16x16x32_f16(a2, bf[2][2], acc[2], 0, 0, 0);
        acc[2] = __builtin_amdgcn_mfma_f32_16x16x32_f16(a3, bf[2][3], acc[2], 0, 0, 0);
        float gg0 = tnhf(acc[2][0]);
        float gg1 = tnhf(acc[2][1]);

        acc[3] = __builtin_amdgcn_mfma_f32_16x16x32_f16(a0, bf[3][0], acc[3], 0, 0, 0);
        acc[3] = __builtin_amdgcn_mfma_f32_16x16x32_f16(a1, bf[3][1], acc[3], 0, 0, 0);
        acc[3] = __builtin_amdgcn_mfma_f32_16x16x32_f16(a2, bf[3][2], acc[3], 0, 0, 0);
        acc[3] = __builtin_amdgcn_mfma_f32_16x16x32_f16(a3, bf[3][3], acc[3], 0, 0, 0);
        float oo0 = sigf(acc[3][0]);
        float oo1 = sigf(acc[3][1]);

        // state update + h-writes (q = 0, 1)
        float cn0 = ff0 * c2[0] + ii0 * gg0;
        c2[0] = cn0;
        float hn0 = oo0 * tnhf(cn0);
        h2[0] = hn0;
        *reinterpret_cast<_Float16*>(wc + wr0) = (_Float16)hn0;

        float cn1 = ff1 * c2[1] + ii1 * gg1;
        c2[1] = cn1;
        float hn1 = oo1 * tnhf(cn1);
        h2[1] = hn1;
        *reinterpret_cast<_Float16*>(wc + wr1) = (_Float16)hn1;

        p = qn; qn = rn;
        lgkm_barrier();
    }

    #pragma unroll
    for (int q = 0; q < 2; ++q) {
        int b = bq * 16 + hi * 8 + (g4 & 1) * 4 + (g4 >> 1) * 2 + q;
        hf[((size_t)b * NN + n) * HID + j] = h2[q];
    }
}

// Head: 64 blocks (one per batch row), 256 thr, split-K over 2 halves.
__global__ __launch_bounds__(256) void head2_kernel(
        const float* __restrict__ hf, const float* __restrict__ w1t,
        const float* __restrict__ b1, const float* __restrict__ W2,
        const float* __restrict__ b2, float* __restrict__ out) {
    __shared__ float comb[FEAT];
    __shared__ float par[2][HID];
    __shared__ float hid[HID];
    const int b = blockIdx.x;
    const int u  = threadIdx.x & 127;
    const int kk = threadIdx.x >> 7;
    const float* hfp = hf + (size_t)b * FEAT;
    for (int i = threadIdx.x; i < FEAT; i += 256) comb[i] = hfp[i];
    __syncthreads();

    const int k0 = kk * (FEAT / 2);
    float acc = 0.f;
    #pragma unroll 8
    for (int k = 0; k < FEAT / 2; ++k)
        acc = fmaf(comb[k0 + k], w1t[(size_t)(k0 + k) * HID + u], acc);
    par[kk][u] = acc;
    __syncthreads();
    if (kk == 0) hid[u] = fmaxf(par[0][u] + par[1][u] + b1[u], 0.f);
    __syncthreads();

    if (threadIdx.x < NC) {
        int cls = threadIdx.x;
        float a = b2[cls];
        #pragma unroll 4
        for (int k = 0; k < HID; ++k)
            a = fmaf(hid[k], W2[cls * HID + k], a);
        out[b * NC + cls] = a;
    }
}

// ======================= fallback (round-3) =======================
__global__ __launch_bounds__(256) void packfb_kernel(
        const float* __restrict__ W_ih, const float* __restrict__ W_hh,
        const float* __restrict__ W1,
        unsigned short* __restrict__ bfw, float* __restrict__ w1t) {
    int id = blockIdx.x * 256 + threadIdx.x;
    if (id < SZ_BF) {
        int e    = id & 7;
        int lane = (id >> 3) & 63;
        int kt   = (id >> 9) & 7;
        int nt   = (id >> 12) & 3;
        int hb   = (id >> 14) & 7;
        int n    = id >> 17;
        int k = kt * 32 + (lane >> 4) * 8 + e;
        int g = nt * 128 + hb * 16 + (lane & 15);
        float v = 0.f;
        if (k < DIN)       v = W_ih[((size_t)n * 512 + g) * DIN + k];
        else if (k < 228)  v = W_hh[((size_t)n * 512 + g) * HID + (k - DIN)];
        bfw[id] = f2bf(v);
        return;
    }
    int id3 = id - SZ_BF;
    if (id3 < SZ_W1T) {
        int j = id3 & 127, k = id3 >> 7;
        w1t[id3] = W1[(size_t)j * FEAT + k];
    }
}

__global__ __launch_bounds__(512, 2) void lstmfb_kernel(
        const float* __restrict__ inp,
        const float* __restrict__ b_ih, const float* __restrict__ b_hh,
        const unsigned short* __restrict__ bfw, float* __restrict__ hf) {
    __shared__ alignas(16) unsigned short xh[2][16 * 256];
    const int tid  = threadIdx.x;
    const int lane = tid & 63;
    const int w    = tid >> 6;
    const int l15  = lane & 15;
    const int g4   = lane >> 4;
    const int n    = blockIdx.x >> 2;
    const int bq   = blockIdx.x & 3;
    const int j    = w * 16 + l15;

    s8v bf[4][8];
    const unsigned short* wp = bfw + ((size_t)(n * 8 + w) * 32) * 512 + lane * 8;
    #pragma unroll
    for (int nt = 0; nt < 4; ++nt)
        #pragma unroll
        for (int kt = 0; kt < 8; ++kt)
            bf[nt][kt] = *reinterpret_cast<const s8v*>(wp + (nt * 8 + kt) * 512);

    float bs[4];
    #pragma unroll
    for (int nt = 0; nt < 4; ++nt)
        bs[nt] = b_ih[n * 512 + nt * 128 + j] + b_hh[n * 512 + nt * 128 + j];

    float c[4] = {0.f, 0.f, 0.f, 0.f};
    float h[4] = {0.f, 0.f, 0.f, 0.f};
    for (int i = tid; i < 2 * 16 * 256; i += 512) (&xh[0][0])[i] = 0;

    const bool st = tid < 400;
    const int row = st ? tid / 25 : 0;
    const int c4  = st ? tid - row * 25 : 0;
    const float* xb = inp + ((size_t)(bq * 16 + row) * NN + n) * (TT * DIN) + c4 * 4;
    const int wofs = row * 512 + ((c4 * 8) ^ ((row & 7) << 4));
    const int arow = l15 * 512;
    const int aswz = (l15 & 7) << 4;

    __syncthreads();
    if (st) {
        float4 v = *reinterpret_cast<const float4*>(xb);
        unsigned lo = f2bf(v.x) | ((unsigned)f2bf(v.y) << 16);
        unsigned hi = f2bf(v.z) | ((unsigned)f2bf(v.w) << 16);
        *reinterpret_cast<uint2*>(reinterpret_cast<char*>(xh[0]) + wofs) =
            make_uint2(lo, hi);
    }
    __syncthreads();

    for (int t = 0; t < TT; ++t) {
        char* rc = reinterpret_cast<char*>(xh[t & 1]);
        char* wc = reinterpret_cast<char*>(xh[(t + 1) & 1]);
        float4 nxt = make_float4(0.f, 0.f, 0.f, 0.f);
        if (t < TT - 1 && st)
            nxt = *reinterpret_cast<const float4*>(xb + (t + 1) * DIN);

        f4v acc[4];
        #pragma unroll
        for (int nt = 0; nt < 4; ++nt)
            acc[nt] = (f4v){bs[nt], bs[nt], bs[nt], bs[nt]};
        #pragma unroll
        for (int kt = 0; kt < 8; ++kt) {
            s8v a = *reinterpret_cast<const s8v*>(rc + arow + ((kt * 64 + g4 * 16) ^ aswz));
            #pragma unroll
            for (int nt = 0; nt < 4; ++nt)
                acc[nt] = __builtin_amdgcn_mfma_f32_16x16x32_bf16(a, bf[nt][kt], acc[nt], 0, 0, 0);
        }
        #pragma unroll
        for (int r = 0; r < 4; ++r) {
            float ii = sigf(acc[0][r]);
            float ff = sigf(acc[1][r]);
            float gg = tnhf(acc[2][r]);
            float oo = sigf(acc[3][r]);
            float cn = ff * c[r] + ii * gg;
            c[r] = cn;
            float hn = oo * tnhf(cn);
            h[r] = hn;
            int rr = g4 * 4 + r;
            *reinterpret_cast<unsigned short*>(
                wc + rr * 512 + (((DIN + j) * 2) ^ ((rr & 7) << 4))) = f2bf(hn);
        }
        if (t < TT - 1 && st) {
            unsigned lo = f2bf(nxt.x) | ((unsigned)f2bf(nxt.y) << 16);
            unsigned hi = f2bf(nxt.z) | ((unsigned)f2bf(nxt.w) << 16);
            *reinterpret_cast<uint2*>(wc + wofs) = make_uint2(lo, hi);
        }
        __syncthreads();
    }
    #pragma unroll
    for (int r = 0; r < 4; ++r) {
        int b = bq * 16 + g4 * 4 + r;
        hf[((size_t)b * NN + n) * HID + j] = h[r];
    }
}

// ============================ launch ==============================
extern "C" void kernel_launch(void* const* d_in, const int* in_sizes, int n_in,
                              void* d_out, int out_size, void* d_ws, size_t ws_size,
                              hipStream_t stream) {
    const float* inp  = (const float*)d_in[0];
    const float* W_ih = (const float*)d_in[2];
    const float* W_hh = (const float*)d_in[3];
    const float* b_ih = (const float*)d_in[4];
    const float* b_hh = (const float*)d_in[5];
    const float* W1   = (const float*)d_in[6];
    const float* b1   = (const float*)d_in[7];
    const float* W2   = (const float*)d_in[8];
    const float* b2   = (const float*)d_in[9];
    float* out = (float*)d_out;

    if (ws_size >= V2_NEED) {
        char* wsb = (char*)d_ws;
        _Float16* xg = (_Float16*)(wsb + V2_OFF_XG);
        float* hf    = (float*)(wsb + V2_OFF_HF);
        float* w1t   = (float*)(wsb + V2_OFF_W1T);
        pack2_kernel<<<(PACK2_TOTAL + 255) / 256, 256, 0, stream>>>(
            W_ih, W_hh, b_ih, b_hh, W1, wsb);
        xg_kernel<<<NN * 4 * 10, 512, 0, stream>>>(inp, wsb, xg);
        lstm7_kernel<<<NN * 8, 512, 0, stream>>>(wsb, xg, hf);
        head2_kernel<<<BB, 256, 0, stream>>>(hf, w1t, b1, W2, b2, out);
    } else {
        float* ws = (float*)d_ws;
        unsigned short* bfw = (unsigned short*)d_ws;
        packfb_kernel<<<(PACK_TOTAL_O + 255) / 256, 256, 0, stream>>>(
            W_ih, W_hh, W1, bfw, ws + OFF_W1T_O);
        lstmfb_kernel<<<NN * 4, 512, 0, stream>>>(inp, b_ih, b_hh, bfw, ws + OFF_HF_O);
        head2_kernel<<<BB, 256, 0, stream>>>(ws + OFF_HF_O, ws + OFF_W1T_O,
                                             b1, W2, b2, out);
    }
}

// Round 11
// 333.485 us; speedup vs baseline: 1.2168x; 1.1255x over previous
//
#include <hip/hip_runtime.h>
#include <hip/hip_bf16.h>

#define NN   19
#define DIN  100
#define HID  128
#define TT   250
#define BB   64
#define NC   4
#define FEAT 2432          // NN*HID

typedef __attribute__((ext_vector_type(8))) short s8v;
typedef __attribute__((ext_vector_type(4))) float f4v;
typedef _Float16 h8v __attribute__((ext_vector_type(8)));
typedef _Float16 h4v __attribute__((ext_vector_type(4)));

// =============== V2 workspace layout (byte offsets) ===============
// BFI: W_ih MFMA B-frags f16  (19*8*4*4*512 halfs; per node 65536 halfs)
// BFH: W_hh MFMA B-frags f16  (same count)
// BIAS: combined b_ih+b_hh f32 (19*512)
// W1T: W1 transposed f32 (2432*128) ; HF: final hidden f32 (64*2432)
#define BFI_USH   1245184
#define V2_OFF_BFI  0ull
#define V2_OFF_BFH  2490368ull
#define V2_OFF_BIAS 4980736ull
#define V2_OFF_W1T  5019648ull
#define V2_OFF_HF   6264832ull
#define V2_NEED     6887424ull
#define PACK2_TOTAL (2*BFI_USH + 19*512 + FEAT*HID)

// =============== fallback (round-3) layout, float offsets =========
#define SZ_BF   (NN*8*4*8*512)
#define OFF_W1T_O (SZ_BF/2)
#define SZ_W1T  (FEAT*HID)
#define OFF_HF_O  (OFF_W1T_O + SZ_W1T)
#define PACK_TOTAL_O (SZ_BF + SZ_W1T)

__device__ __forceinline__ unsigned short f2bf(float x) {
    union { float f; unsigned u; } v; v.f = x;
    unsigned r = v.u + 0x7FFF + ((v.u >> 16) & 1);   // RNE
    return (unsigned short)(r >> 16);
}
#define LOG2E 1.4426950408889634f
__device__ __forceinline__ float sigf(float x) {
    return __builtin_amdgcn_rcpf(1.f + __builtin_amdgcn_exp2f(-LOG2E * x));
}
__device__ __forceinline__ float tnhf(float x) {
    return 1.f - 2.f * __builtin_amdgcn_rcpf(__builtin_amdgcn_exp2f(2.f * LOG2E * x) + 1.f);
}

// lgkm-only barrier: LDS ordered; global loads/stores stay in flight.
__device__ __forceinline__ void lgkm_barrier() {
    asm volatile("s_waitcnt lgkmcnt(0)" ::: "memory");
    __builtin_amdgcn_s_barrier();
    asm volatile("" ::: "memory");
}

// ======================= V2 kernels ===============================

// Pack W_ih frags, W_hh frags (f16), combined bias, W1T.
// Frag element (n, hb, nt, kt, lane, e) = W[k][g]:
// k = kt*32+(lane>>4)*8+e, g = nt*128+hb*16+(lane&15).
__global__ __launch_bounds__(256) void pack2_kernel(
        const float* __restrict__ W_ih, const float* __restrict__ W_hh,
        const float* __restrict__ b_ih, const float* __restrict__ b_hh,
        const float* __restrict__ W1, char* __restrict__ wsb) {
    int id = blockIdx.x * 256 + threadIdx.x;
    if (id < 2 * BFI_USH) {
        int which = id >= BFI_USH;                 // 0 = W_ih, 1 = W_hh
        int i = which ? id - BFI_USH : id;
        int e    = i & 7;
        int lane = (i >> 3) & 63;
        int kt   = (i >> 9) & 3;
        int nt   = (i >> 11) & 3;
        int hb   = (i >> 13) & 7;
        int n    = i >> 16;
        int k = kt * 32 + (lane >> 4) * 8 + e;
        int g = nt * 128 + hb * 16 + (lane & 15);
        float v;
        if (which) v = W_hh[((size_t)n * 512 + g) * HID + k];
        else       v = (k < DIN) ? W_ih[((size_t)n * 512 + g) * DIN + k] : 0.f;
        reinterpret_cast<_Float16*>(wsb)[id] = (_Float16)v;
        return;
    }
    int id2 = id - 2 * BFI_USH;
    if (id2 < NN * 512) {
        reinterpret_cast<float*>(wsb + V2_OFF_BIAS)[id2] = b_ih[id2] + b_hh[id2];
        return;
    }
    int id3 = id2 - NN * 512;
    if (id3 < FEAT * HID) {
        int j = id3 & 127, k = id3 >> 7;
        reinterpret_cast<float*>(wsb + V2_OFF_W1T)[id3] = W1[(size_t)j * FEAT + k];
    }
}

// Fused recurrence v8: grid 152 = (n, batch-octet). 512 thr = 8 waves,
// wave hb owns 16 hidden j. Gate GEMM is FUSED over K=256 ([x|h]):
//  - W_hh frags in registers (16 h8v)
//  - W_ih frags in LDS (128 KB, loaded once, re-read per step)
//  - x(t) staged to LDS by 200 threads (float4 -> f16), 1-step prefetch
// A-tile [16][256] f16, permuted dup map: tile row g4*4+q (q=0,1) holds
// real octet row R=(g4&1)*4+(g4>>1)*2+q; other rows stay zero.
// Removes the xg intermediate (622 MB HBM round-trip) entirely.
__global__ __launch_bounds__(512, 2) void lstm8_kernel(
        const char* __restrict__ wsb, const float* __restrict__ inp,
        float* __restrict__ hf) {
    __shared__ alignas(16) _Float16 wih[8 * 16 * 512];   // 128 KB
    __shared__ alignas(16) _Float16 xh[2][16 * 256];     // 16 KB

    const int tid  = threadIdx.x;
    const int lane = tid & 63;
    const int w8   = tid >> 6;          // 0..7
    const int l15  = lane & 15;
    const int g4   = lane >> 4;
    const int n    = blockIdx.x >> 3;
    const int oct  = blockIdx.x & 7;
    const int bq   = oct >> 1;
    const int hi   = oct & 1;
    const int hb   = w8;
    const int j    = hb * 16 + l15;

    // W_hh frags in regs (16 h8v)
    h8v bf[4][4];
    {
        const _Float16* wp = reinterpret_cast<const _Float16*>(wsb + V2_OFF_BFH)
                             + (size_t)lane * 8;
        #pragma unroll
        for (int nt = 0; nt < 4; ++nt)
            #pragma unroll
            for (int kt = 0; kt < 4; ++kt)
                bf[nt][kt] = *reinterpret_cast<const h8v*>(
                    wp + ((size_t)((n * 8 + hb) * 16 + nt * 4 + kt)) * 512);
    }
    float bs[4];
    #pragma unroll
    for (int nt = 0; nt < 4; ++nt)
        bs[nt] = reinterpret_cast<const float*>(wsb + V2_OFF_BIAS)[n * 512 + nt * 128 + j];

    // W_ih frags -> LDS (128 KB, coalesced 16 iters)
    {
        const h8v* src = reinterpret_cast<const h8v*>(
            reinterpret_cast<const _Float16*>(wsb + V2_OFF_BFI) + (size_t)n * 65536);
        h8v* dst = reinterpret_cast<h8v*>(wih);
        for (int i = tid; i < 8192; i += 512) dst[i] = src[i];
    }
    // zero xh (both buffers; pad rows/cols must stay 0)
    for (int i = tid; i < 2 * 16 * 256; i += 512) (&xh[0][0])[i] = (_Float16)0.f;

    // x staging: 200 threads, 8 live tile rows x 25 float4
    const bool st = tid < 200;
    const int sr  = st ? tid / 25 : 0;
    const int c4  = st ? tid - sr * 25 : 0;
    const int g4s = sr >> 1, qs = sr & 1;
    const int tr  = g4s * 4 + qs;                         // live tile row
    const int Rr  = (g4s & 1) * 4 + (g4s >> 1) * 2 + qs;  // real octet row
    const float* xb = inp + (size_t)((bq * 16 + hi * 8 + Rr) * NN + n) * (TT * DIN)
                      + c4 * 4;
    const int wofs_x = tr * 512 + ((c4 * 8) ^ ((tr & 7) << 4));

    const int arow = l15 * 512;
    const int aswz = (l15 & 7) << 4;
    const int wr0 = (g4 * 4) * 512 + ((256 + 2 * j) ^ (((g4 * 4) & 7) << 4));
    const int wr1 = (g4 * 4 + 1) * 512 + ((256 + 2 * j) ^ (((g4 * 4 + 1) & 7) << 4));
    const char* wfb = reinterpret_cast<const char*>(wih) + hb * 16384 + lane * 16;

    float c2[2] = {0.f, 0.f};
    float h2[2] = {0.f, 0.f};

    __syncthreads();
    if (st) {   // stage x(0) into buffer 0
        float4 v = *reinterpret_cast<const float4*>(xb);
        h4v pk = {(_Float16)v.x, (_Float16)v.y, (_Float16)v.z, (_Float16)v.w};
        *reinterpret_cast<h4v*>(reinterpret_cast<char*>(xh[0]) + wofs_x) = pk;
    }
    __syncthreads();

    #pragma unroll 2
    for (int t = 0; t < TT; ++t) {
        char* rc = reinterpret_cast<char*>(xh[t & 1]);
        char* wc = reinterpret_cast<char*>(xh[(t + 1) & 1]);

        // issue x(t+1) load; lands before write phase (lgkm barriers
        // never drain vmcnt, so it can span most of the step)
        float4 nxt = make_float4(0.f, 0.f, 0.f, 0.f);
        if (t < TT - 1 && st)
            nxt = *reinterpret_cast<const float4*>(xb + (t + 1) * DIN);

        f4v acc[4];
        #pragma unroll
        for (int nt = 0; nt < 4; ++nt)
            acc[nt] = (f4v){bs[nt], bs[nt], 0.f, 0.f};

        // ---- phase X: x-part A frags + W_ih (LDS) MFMAs ----
        h8v ax0 = *reinterpret_cast<const h8v*>(rc + arow + ((0 * 64 + g4 * 16) ^ aswz));
        h8v ax1 = *reinterpret_cast<const h8v*>(rc + arow + ((1 * 64 + g4 * 16) ^ aswz));
        h8v ax2 = *reinterpret_cast<const h8v*>(rc + arow + ((2 * 64 + g4 * 16) ^ aswz));
        h8v ax3 = *reinterpret_cast<const h8v*>(rc + arow + ((3 * 64 + g4 * 16) ^ aswz));
        #pragma unroll
        for (int nt = 0; nt < 4; ++nt) {
            h8v w0 = *reinterpret_cast<const h8v*>(wfb + (nt * 4 + 0) * 1024);
            h8v w1 = *reinterpret_cast<const h8v*>(wfb + (nt * 4 + 1) * 1024);
            h8v w2 = *reinterpret_cast<const h8v*>(wfb + (nt * 4 + 2) * 1024);
            h8v w3 = *reinterpret_cast<const h8v*>(wfb + (nt * 4 + 3) * 1024);
            acc[nt] = __builtin_amdgcn_mfma_f32_16x16x32_f16(ax0, w0, acc[nt], 0, 0, 0);
            acc[nt] = __builtin_amdgcn_mfma_f32_16x16x32_f16(ax1, w1, acc[nt], 0, 0, 0);
            acc[nt] = __builtin_amdgcn_mfma_f32_16x16x32_f16(ax2, w2, acc[nt], 0, 0, 0);
            acc[nt] = __builtin_amdgcn_mfma_f32_16x16x32_f16(ax3, w3, acc[nt], 0, 0, 0);
        }

        // ---- phase H: h-part A frags + W_hh (reg) MFMAs, early nonlin ----
        h8v ah0 = *reinterpret_cast<const h8v*>(rc + arow + ((4 * 64 + g4 * 16) ^ aswz));
        h8v ah1 = *reinterpret_cast<const h8v*>(rc + arow + ((5 * 64 + g4 * 16) ^ aswz));
        h8v ah2 = *reinterpret_cast<const h8v*>(rc + arow + ((6 * 64 + g4 * 16) ^ aswz));
        h8v ah3 = *reinterpret_cast<const h8v*>(rc + arow + ((7 * 64 + g4 * 16) ^ aswz));

        acc[0] = __builtin_amdgcn_mfma_f32_16x16x32_f16(ah0, bf[0][0], acc[0], 0, 0, 0);
        acc[0] = __builtin_amdgcn_mfma_f32_16x16x32_f16(ah1, bf[0][1], acc[0], 0, 0, 0);
        acc[0] = __builtin_amdgcn_mfma_f32_16x16x32_f16(ah2, bf[0][2], acc[0], 0, 0, 0);
        acc[0] = __builtin_amdgcn_mfma_f32_16x16x32_f16(ah3, bf[0][3], acc[0], 0, 0, 0);
        float ii0 = sigf(acc[0][0]);
        float ii1 = sigf(acc[0][1]);

        acc[1] = __builtin_amdgcn_mfma_f32_16x16x32_f16(ah0, bf[1][0], acc[1], 0, 0, 0);
        acc[1] = __builtin_amdgcn_mfma_f32_16x16x32_f16(ah1, bf[1][1], acc[1], 0, 0, 0);
        acc[1] = __builtin_amdgcn_mfma_f32_16x16x32_f16(ah2, bf[1][2], acc[1], 0, 0, 0);
        acc[1] = __builtin_amdgcn_mfma_f32_16x16x32_f16(ah3, bf[1][3], acc[1], 0, 0, 0);
        float ff0 = sigf(acc[1][0]);
        float ff1 = sigf(acc[1][1]);

        acc[2] = __builtin_amdgcn_mfma_f32_16x16x32_f16(ah0, bf[2][0], acc[2], 0, 0, 0);
        acc[2] = __builtin_amdgcn_mfma_f32_16x16x32_f16(ah1, bf[2][1], acc[2], 0, 0, 0);
        acc[2] = __builtin_amdgcn_mfma_f32_16x16x32_f16(ah2, bf[2][2], acc[2], 0, 0, 0);
        acc[2] = __builtin_amdgcn_mfma_f32_16x16x32_f16(ah3, bf[2][3], acc[2], 0, 0, 0);
        float gg0 = tnhf(acc[2][0]);
        float gg1 = tnhf(acc[2][1]);

        acc[3] = __builtin_amdgcn_mfma_f32_16x16x32_f16(ah0, bf[3][0], acc[3], 0, 0, 0);
        acc[3] = __builtin_amdgcn_mfma_f32_16x16x32_f16(ah1, bf[3][1], acc[3], 0, 0, 0);
        acc[3] = __builtin_amdgcn_mfma_f32_16x16x32_f16(ah2, bf[3][2], acc[3], 0, 0, 0);
        acc[3] = __builtin_amdgcn_mfma_f32_16x16x32_f16(ah3, bf[3][3], acc[3], 0, 0, 0);
        float oo0 = sigf(acc[3][0]);
        float oo1 = sigf(acc[3][1]);

        // state update + h(t+1) writes
        float cn0 = ff0 * c2[0] + ii0 * gg0;
        c2[0] = cn0;
        float hn0 = oo0 * tnhf(cn0);
        h2[0] = hn0;
        *reinterpret_cast<_Float16*>(wc + wr0) = (_Float16)hn0;

        float cn1 = ff1 * c2[1] + ii1 * gg1;
        c2[1] = cn1;
        float hn1 = oo1 * tnhf(cn1);
        h2[1] = hn1;
        *reinterpret_cast<_Float16*>(wc + wr1) = (_Float16)hn1;

        // x(t+1) write into next buffer (its x-region was last read at t-1)
        if (t < TT - 1 && st) {
            h4v pk = {(_Float16)nxt.x, (_Float16)nxt.y, (_Float16)nxt.z, (_Float16)nxt.w};
            *reinterpret_cast<h4v*>(wc + wofs_x) = pk;
        }
        lgkm_barrier();
    }

    #pragma unroll
    for (int q = 0; q < 2; ++q) {
        int b = bq * 16 + hi * 8 + (g4 & 1) * 4 + (g4 >> 1) * 2 + q;
        hf[((size_t)b * NN + n) * HID + j] = h2[q];
    }
}

// Head: 64 blocks (one per batch row), 256 thr, split-K over 2 halves.
__global__ __launch_bounds__(256) void head2_kernel(
        const float* __restrict__ hf, const float* __restrict__ w1t,
        const float* __restrict__ b1, const float* __restrict__ W2,
        const float* __restrict__ b2, float* __restrict__ out) {
    __shared__ float comb[FEAT];
    __shared__ float par[2][HID];
    __shared__ float hid[HID];
    const int b = blockIdx.x;
    const int u  = threadIdx.x & 127;
    const int kk = threadIdx.x >> 7;
    const float* hfp = hf + (size_t)b * FEAT;
    for (int i = threadIdx.x; i < FEAT; i += 256) comb[i] = hfp[i];
    __syncthreads();

    const int k0 = kk * (FEAT / 2);
    float acc = 0.f;
    #pragma unroll 8
    for (int k = 0; k < FEAT / 2; ++k)
        acc = fmaf(comb[k0 + k], w1t[(size_t)(k0 + k) * HID + u], acc);
    par[kk][u] = acc;
    __syncthreads();
    if (kk == 0) hid[u] = fmaxf(par[0][u] + par[1][u] + b1[u], 0.f);
    __syncthreads();

    if (threadIdx.x < NC) {
        int cls = threadIdx.x;
        float a = b2[cls];
        #pragma unroll 4
        for (int k = 0; k < HID; ++k)
            a = fmaf(hid[k], W2[cls * HID + k], a);
        out[b * NC + cls] = a;
    }
}

// ======================= fallback (round-3) =======================
__global__ __launch_bounds__(256) void packfb_kernel(
        const float* __restrict__ W_ih, const float* __restrict__ W_hh,
        const float* __restrict__ W1,
        unsigned short* __restrict__ bfw, float* __restrict__ w1t) {
    int id = blockIdx.x * 256 + threadIdx.x;
    if (id < SZ_BF) {
        int e    = id & 7;
        int lane = (id >> 3) & 63;
        int kt   = (id >> 9) & 7;
        int nt   = (id >> 12) & 3;
        int hb   = (id >> 14) & 7;
        int n    = id >> 17;
        int k = kt * 32 + (lane >> 4) * 8 + e;
        int g = nt * 128 + hb * 16 + (lane & 15);
        float v = 0.f;
        if (k < DIN)       v = W_ih[((size_t)n * 512 + g) * DIN + k];
        else if (k < 228)  v = W_hh[((size_t)n * 512 + g) * HID + (k - DIN)];
        bfw[id] = f2bf(v);
        return;
    }
    int id3 = id - SZ_BF;
    if (id3 < SZ_W1T) {
        int j = id3 & 127, k = id3 >> 7;
        w1t[id3] = W1[(size_t)j * FEAT + k];
    }
}

__global__ __launch_bounds__(512, 2) void lstmfb_kernel(
        const float* __restrict__ inp,
        const float* __restrict__ b_ih, const float* __restrict__ b_hh,
        const unsigned short* __restrict__ bfw, float* __restrict__ hf) {
    __shared__ alignas(16) unsigned short xh[2][16 * 256];
    const int tid  = threadIdx.x;
    const int lane = tid & 63;
    const int w    = tid >> 6;
    const int l15  = lane & 15;
    const int g4   = lane >> 4;
    const int n    = blockIdx.x >> 2;
    const int bq   = blockIdx.x & 3;
    const int j    = w * 16 + l15;

    s8v bf[4][8];
    const unsigned short* wp = bfw + ((size_t)(n * 8 + w) * 32) * 512 + lane * 8;
    #pragma unroll
    for (int nt = 0; nt < 4; ++nt)
        #pragma unroll
        for (int kt = 0; kt < 8; ++kt)
            bf[nt][kt] = *reinterpret_cast<const s8v*>(wp + (nt * 8 + kt) * 512);

    float bs[4];
    #pragma unroll
    for (int nt = 0; nt < 4; ++nt)
        bs[nt] = b_ih[n * 512 + nt * 128 + j] + b_hh[n * 512 + nt * 128 + j];

    float c[4] = {0.f, 0.f, 0.f, 0.f};
    float h[4] = {0.f, 0.f, 0.f, 0.f};
    for (int i = tid; i < 2 * 16 * 256; i += 512) (&xh[0][0])[i] = 0;

    const bool st = tid < 400;
    const int row = st ? tid / 25 : 0;
    const int c4  = st ? tid - row * 25 : 0;
    const float* xb = inp + ((size_t)(bq * 16 + row) * NN + n) * (TT * DIN) + c4 * 4;
    const int wofs = row * 512 + ((c4 * 8) ^ ((row & 7) << 4));
    const int arow = l15 * 512;
    const int aswz = (l15 & 7) << 4;

    __syncthreads();
    if (st) {
        float4 v = *reinterpret_cast<const float4*>(xb);
        unsigned lo = f2bf(v.x) | ((unsigned)f2bf(v.y) << 16);
        unsigned hi = f2bf(v.z) | ((unsigned)f2bf(v.w) << 16);
        *reinterpret_cast<uint2*>(reinterpret_cast<char*>(xh[0]) + wofs) =
            make_uint2(lo, hi);
    }
    __syncthreads();

    for (int t = 0; t < TT; ++t) {
        char* rc = reinterpret_cast<char*>(xh[t & 1]);
        char* wc = reinterpret_cast<char*>(xh[(t + 1) & 1]);
        float4 nxt = make_float4(0.f, 0.f, 0.f, 0.f);
        if (t < TT - 1 && st)
            nxt = *reinterpret_cast<const float4*>(xb + (t + 1) * DIN);

        f4v acc[4];
        #pragma unroll
        for (int nt = 0; nt < 4; ++nt)
            acc[nt] = (f4v){bs[nt], bs[nt], bs[nt], bs[nt]};
        #pragma unroll
        for (int kt = 0; kt < 8; ++kt) {
            s8v a = *reinterpret_cast<const s8v*>(rc + arow + ((kt * 64 + g4 * 16) ^ aswz));
            #pragma unroll
            for (int nt = 0; nt < 4; ++nt)
                acc[nt] = __builtin_amdgcn_mfma_f32_16x16x32_bf16(a, bf[nt][kt], acc[nt], 0, 0, 0);
        }
        #pragma unroll
        for (int r = 0; r < 4; ++r) {
            float ii = sigf(acc[0][r]);
            float ff = sigf(acc[1][r]);
            float gg = tnhf(acc[2][r]);
            float oo = sigf(acc[3][r]);
            float cn = ff * c[r] + ii * gg;
            c[r] = cn;
            float hn = oo * tnhf(cn);
            h[r] = hn;
            int rr = g4 * 4 + r;
            *reinterpret_cast<unsigned short*>(
                wc + rr * 512 + (((DIN + j) * 2) ^ ((rr & 7) << 4))) = f2bf(hn);
        }
        if (t < TT - 1 && st) {
            unsigned lo = f2bf(nxt.x) | ((unsigned)f2bf(nxt.y) << 16);
            unsigned hi = f2bf(nxt.z) | ((unsigned)f2bf(nxt.w) << 16);
            *reinterpret_cast<uint2*>(wc + wofs) = make_uint2(lo, hi);
        }
        __syncthreads();
    }
    #pragma unroll
    for (int r = 0; r < 4; ++r) {
        int b = bq * 16 + g4 * 4 + r;
        hf[((size_t)b * NN + n) * HID + j] = h[r];
    }
}

// ============================ launch ==============================
extern "C" void kernel_launch(void* const* d_in, const int* in_sizes, int n_in,
                              void* d_out, int out_size, void* d_ws, size_t ws_size,
                              hipStream_t stream) {
    const float* inp  = (const float*)d_in[0];
    const float* W_ih = (const float*)d_in[2];
    const float* W_hh = (const float*)d_in[3];
    const float* b_ih = (const float*)d_in[4];
    const float* b_hh = (const float*)d_in[5];
    const float* W1   = (const float*)d_in[6];
    const float* b1   = (const float*)d_in[7];
    const float* W2   = (const float*)d_in[8];
    const float* b2   = (const float*)d_in[9];
    float* out = (float*)d_out;

    if (ws_size >= V2_NEED) {
        char* wsb = (char*)d_ws;
        float* hf  = (float*)(wsb + V2_OFF_HF);
        float* w1t = (float*)(wsb + V2_OFF_W1T);
        pack2_kernel<<<(PACK2_TOTAL + 255) / 256, 256, 0, stream>>>(
            W_ih, W_hh, b_ih, b_hh, W1, wsb);
        lstm8_kernel<<<NN * 8, 512, 0, stream>>>(wsb, inp, hf);
        head2_kernel<<<BB, 256, 0, stream>>>(hf, w1t, b1, W2, b2, out);
    } else {
        float* ws = (float*)d_ws;
        unsigned short* bfw = (unsigned short*)d_ws;
        packfb_kernel<<<(PACK_TOTAL_O + 255) / 256, 256, 0, stream>>>(
            W_ih, W_hh, W1, bfw, ws + OFF_W1T_O);
        lstmfb_kernel<<<NN * 4, 512, 0, stream>>>(inp, b_ih, b_hh, bfw, ws + OFF_HF_O);
        head2_kernel<<<BB, 256, 0, stream>>>(ws + OFF_HF_O, ws + OFF_W1T_O,
                                             b1, W2, b2, out);
    }
}